// Round 12
// baseline (548.360 us; speedup 1.0000x reference)
//
#include <hip/hip_runtime.h>
#include <hip/hip_bf16.h>

typedef __bf16 bf16x8_t __attribute__((ext_vector_type(8)));
typedef float  f32x4_t  __attribute__((ext_vector_type(4)));

__device__ inline bf16x8_t ld_bf16x8(const __hip_bfloat16* p) {
    return *reinterpret_cast<const bf16x8_t*>(p);
}
__device__ inline bf16x8_t zero_bf16x8() {
    bf16x8_t z;
#pragma unroll
    for (int i = 0; i < 8; ++i) z[i] = (__bf16)0.0f;
    return z;
}

// Exact 3-way bf16 split: v == h + m + l exactly (truncation-based).
__device__ inline void split3f(float v, __bf16& h, __bf16& m, __bf16& l) {
    unsigned u;  __builtin_memcpy(&u, &v, 4);
    unsigned uh = u & 0xffff0000u;
    float fh;    __builtin_memcpy(&fh, &uh, 4);
    float r = v - fh;
    unsigned ur; __builtin_memcpy(&ur, &r, 4);
    unsigned um = ur & 0xffff0000u;
    float fm;    __builtin_memcpy(&fm, &um, 4);
    float r2 = r - fm;
    unsigned ul; __builtin_memcpy(&ul, &r2, 4);
    unsigned short hs = (unsigned short)(uh >> 16);
    unsigned short ms = (unsigned short)(um >> 16);
    unsigned short ls = (unsigned short)(ul >> 16);
    __builtin_memcpy(&h, &hs, 2);
    __builtin_memcpy(&m, &ms, 2);
    __builtin_memcpy(&l, &ls, 2);
}

// ---------------------------------------------------------------------------
// enc1 via MFMA: conv 4x4 s2 pad1, CIN=3, COUT=32, bf16x3 exact-split.
// Block = one (n, ho) output row (64 pixels), 4 waves x 16 pixels.
// LDS: 3 planes x 4 input rows x 132 cols x 4 slots (c=0..2 + zero pad).
// K=32 chunk rp: k = lr*16 + s*4 + c (lr = row within pair); every quad's
// 8 elements are one aligned contiguous b128 in LDS.
// B: 12 fragments (rp x tile x plane) in VGPRs, prepped zero-padded.
// ---------------------------------------------------------------------------
__global__ __launch_bounds__(256) void enc1_mfma(
    const float* __restrict__ x,
    const __hip_bfloat16* __restrict__ wb,
    const float* __restrict__ bias, float* __restrict__ y)
{
    __shared__ bf16x8_t xs8[1584];    // 3 * 4*132*4 / 8 units = 25344 B
    __hip_bfloat16* xs = (__hip_bfloat16*)xs8;

    const int n  = blockIdx.x >> 6;
    const int ho = blockIdx.x & 63;
    const int t  = threadIdx.x;
    const int wave = t >> 6, lane = t & 63;
    const int l15 = lane & 15, quad = lane >> 4;

    // B fragments: [rp][tile][plane][lane][8]
    bf16x8_t bf[2][2][3];
#pragma unroll
    for (int rp = 0; rp < 2; ++rp)
#pragma unroll
        for (int tile = 0; tile < 2; ++tile)
#pragma unroll
            for (int pl = 0; pl < 3; ++pl)
                bf[rp][tile][pl] = ld_bf16x8(wb + (size_t)((((rp*2 + tile)*3 + pl)*64 + lane))*8);

    // stage rows 2ho-1 .. 2ho+2, cols -1..130, with exact 3-way split
    const int hi0 = 2*ho - 1;
    for (int slot = t; slot < 4*132*4; slot += 256) {
        int row = slot / 528;
        int rem = slot - row*528;
        int col = rem >> 2, c = rem & 3;
        int hi = hi0 + row, wi = col - 1;
        float v = 0.0f;
        if (c < 3 && hi >= 0 && hi < 128 && wi >= 0 && wi < 128)
            v = x[((size_t)((n*128 + hi))*128 + wi)*3 + c];
        __bf16 h, m, l;
        split3f(v, h, m, l);
        xs[0*2112 + slot] = *(__hip_bfloat16*)&h;
        xs[1*2112 + slot] = *(__hip_bfloat16*)&m;
        xs[2*2112 + slot] = *(__hip_bfloat16*)&l;
    }
    __syncthreads();

    const int wo = wave*16 + l15;
    f32x4_t acc[2];
#pragma unroll
    for (int tile = 0; tile < 2; ++tile) {
        float bv = bias[tile*16 + l15];
        acc[tile][0] = bv; acc[tile][1] = bv; acc[tile][2] = bv; acc[tile][3] = bv;
    }

#pragma unroll
    for (int rp = 0; rp < 2; ++rp) {
        // A frag: element (row = 2rp + (quad>>1), slotcol = 8*wo + (quad&1)*8)
        const int off = (2*rp + (quad >> 1))*528 + 8*wo + (quad & 1)*8;
        bf16x8_t ah = *(const bf16x8_t*)(xs + 0*2112 + off);
        bf16x8_t am = *(const bf16x8_t*)(xs + 1*2112 + off);
        bf16x8_t al = *(const bf16x8_t*)(xs + 2*2112 + off);
#pragma unroll
        for (int tile = 0; tile < 2; ++tile) {
            acc[tile] = __builtin_amdgcn_mfma_f32_16x16x32_bf16(al, bf[rp][tile][0], acc[tile], 0, 0, 0);
            acc[tile] = __builtin_amdgcn_mfma_f32_16x16x32_bf16(ah, bf[rp][tile][2], acc[tile], 0, 0, 0);
            acc[tile] = __builtin_amdgcn_mfma_f32_16x16x32_bf16(am, bf[rp][tile][1], acc[tile], 0, 0, 0);
            acc[tile] = __builtin_amdgcn_mfma_f32_16x16x32_bf16(am, bf[rp][tile][0], acc[tile], 0, 0, 0);
            acc[tile] = __builtin_amdgcn_mfma_f32_16x16x32_bf16(ah, bf[rp][tile][1], acc[tile], 0, 0, 0);
            acc[tile] = __builtin_amdgcn_mfma_f32_16x16x32_bf16(ah, bf[rp][tile][0], acc[tile], 0, 0, 0);
        }
    }

#pragma unroll
    for (int tile = 0; tile < 2; ++tile)
#pragma unroll
        for (int i = 0; i < 4; ++i) {
            int wo2 = wave*16 + quad*4 + i;
            float vv = fmaxf(acc[tile][i], 0.0f);
            y[((size_t)((n*64 + ho))*64 + wo2)*32 + tile*16 + l15] = vv;
        }
}

// enc1 B prep: w [4][4][3][32] HWIO -> [rp][tile][plane][lane][8],
// k = lr*16 + s*4 + c, zero at c==3; f = tile*16 + (lane&15).
__global__ void prep_wb1(const float* __restrict__ w, __hip_bfloat16* __restrict__ out)
{
    int i = blockIdx.x*256 + threadIdx.x;
    if (i >= 2*2*3*64*8) return;
    int j = i & 7;
    int lane = (i >> 3) & 63;
    int g = i >> 9;                 // g = (rp*2 + tile)*3 + pl
    int pl = g % 3; g /= 3;
    int tile = g & 1, rp = g >> 1;
    int k = (lane >> 4)*8 + j;
    int c = k & 3, s = (k >> 2) & 3, lr = k >> 4;
    int f = tile*16 + (lane & 15);
    float v = 0.0f;
    if (c < 3) v = w[(((rp*2 + lr)*4 + s)*3 + c)*32 + f];
    __bf16 h, m, l;
    split3f(v, h, m, l);
    ((__bf16*)out)[i] = (pl == 0) ? h : (pl == 1) ? m : l;
}

// ---------------------------------------------------------------------------
// Weight prep (validated layouts).
// ---------------------------------------------------------------------------
__global__ void prep_wpk(const float* __restrict__ w, __hip_bfloat16* __restrict__ out,
                         int TAPS, int CIN, int COUT)
{
    const int NF = COUT >> 4, KC = CIN >> 5;
    int total = TAPS*3*NF*KC*512;
    int i = blockIdx.x*256 + threadIdx.x;
    if (i >= total) return;
    int tmp = i;
    int j = tmp & 7;      tmp >>= 3;
    int lane = tmp & 63;  tmp >>= 6;
    int kc = tmp % KC;    tmp /= KC;
    int nf = tmp % NF;    tmp /= NF;
    int plane = tmp % 3;  int tap = tmp / 3;
    int l15 = lane & 15, quad = lane >> 4;
    int f = nf*16 + l15;
    int c = kc*32 + quad*8 + j;
    float v = w[(tap*CIN + c)*COUT + f];
    __bf16 h, m, l;
    split3f(v, h, m, l);
    ((__bf16*)out)[i] = (plane == 0) ? h : (plane == 1) ? m : l;
}

__global__ void prep_wdk(const float* __restrict__ w, __hip_bfloat16* __restrict__ out,
                         int TAPS, int CIN, int COUT)
{
    const int NF = COUT >> 4, KC = CIN >> 5;
    int total = TAPS*NF*KC*512;
    int i = blockIdx.x*256 + threadIdx.x;
    if (i >= total) return;
    int tmp = i;
    int j = tmp & 7;      tmp >>= 3;
    int lane = tmp & 63;  tmp >>= 6;
    int kc = tmp % KC;    tmp /= KC;
    int nf = tmp % NF;    tmp /= NF;
    int tap = tmp;
    int l15 = lane & 15, quad = lane >> 4;
    int f = nf*16 + l15;
    int c = kc*32 + quad*8 + j;
    out[i] = __float2bfloat16(w[(tap*CIN + c)*COUT + f]);
}

__global__ void prep_wb4(const float* __restrict__ w, __hip_bfloat16* __restrict__ out)
{
    int i = blockIdx.x*256 + threadIdx.x;
    if (i >= 16*64*8) return;
    int j = i & 7;
    int lane = (i >> 3) & 63;
    int g = i >> 9;
    int f = lane & 15;
    int c = (lane >> 4)*8 + j;
    float v = (f < 3) ? w[g*96 + c*3 + f] : 0.0f;
    out[i] = __float2bfloat16(v);
}

__global__ void prep_wek(const float* __restrict__ emb, __hip_bfloat16* __restrict__ out)
{
    int i = blockIdx.x*256 + threadIdx.x;
    if (i >= 32*2*3*512) return;
    int tmp = i;
    int j = tmp & 7;      tmp >>= 3;
    int lane = tmp & 63;  tmp >>= 6;
    int plane = tmp % 3;  tmp /= 3;
    int kc = tmp & 1;     int nf = tmp >> 1;
    int code = nf*16 + (lane & 15);
    int c = kc*32 + (lane >> 4)*8 + j;
    float v = emb[code*64 + c];
    __bf16 h, m, l;
    split3f(v, h, m, l);
    ((__bf16*)out)[i] = (plane == 0) ? h : (plane == 1) ? m : l;
}

__global__ void prep_se(const float* __restrict__ emb, float* __restrict__ se)
{
    int k = blockIdx.x*256 + threadIdx.x;
    if (k >= 512) return;
    float s = 0.0f;
    for (int d = 0; d < 64; ++d) {
        float e = emb[k*64 + d];
        s = fmaf(e, e, s);
    }
    se[k] = s;
}

// ---------------------------------------------------------------------------
// bf16x3 MFMA encoder conv, B staged per-tap in LDS (validated).
// ---------------------------------------------------------------------------
template<int R,int S,int CIN,int COUT,int IWL,int OWL,int STR,int PAD,int ACT,int INF32,int OUTF32,int NSPLIT>
__global__ __launch_bounds__(256) void mfma_encB(
    const void* __restrict__ xin,
    const __hip_bfloat16* __restrict__ wpk,
    const float* __restrict__ bias,
    __hip_bfloat16* __restrict__ yout,
    float* __restrict__ yf)
{
    constexpr int IW = 1 << IWL, OW = 1 << OWL;
    constexpr int NF = COUT / 16, KC = CIN / 32, TAPS = R*S;
    constexpr int NFB = NF / NSPLIT;
    constexpr int PIECE = NFB*KC*64;
    constexpr int CHUNK8 = 3*PIECE;
    __shared__ bf16x8_t ldsB[CHUNK8];

    const int nf0 = (int)blockIdx.y * NFB;
    const int t = threadIdx.x;
    const int wave = t >> 6, lane = t & 63;
    const int l15 = lane & 15, quad = lane >> 4;

    const int m  = blockIdx.x*64 + wave*16 + l15;
    const int wp_ = m & (OW-1);
    const int hp_ = (m >> OWL) & (OW-1);
    const int np_ = m >> (2*OWL);

    f32x4_t acc[NFB];
#pragma unroll
    for (int nf = 0; nf < NFB; ++nf) {
        float bv = bias[(nf0 + nf)*16 + l15];
        acc[nf][0] = bv; acc[nf][1] = bv; acc[nf][2] = bv; acc[nf][3] = bv;
    }
    const bf16x8_t zv = zero_bf16x8();

    for (int tap = 0; tap < TAPS; ++tap) {
        __syncthreads();
        {
            const bf16x8_t* base = (const bf16x8_t*)wpk + (size_t)tap*(3*NF*KC*64);
            for (int i8 = t; i8 < CHUNK8; i8 += 256) {
                int plane = i8 / PIECE;
                int rem = i8 - plane*PIECE;
                ldsB[i8] = base[(size_t)(plane*NF + nf0)*KC*64 + rem];
            }
        }
        __syncthreads();

        const int r = tap / S, s = tap % S;
        const int hi = hp_*STR - PAD + r;
        const int wi = wp_*STR - PAD + s;
        const bool v = (hi >= 0) && (hi < IW) && (wi >= 0) && (wi < IW);
        const int hic = v ? hi : 0, wic = v ? wi : 0;
        const size_t pix = (size_t)(np_*IW + hic)*IW + wic;

#pragma unroll
        for (int kc = 0; kc < KC; ++kc) {
            bf16x8_t ah, am_, al_;
            if (INF32) {
                const float* af = (const float*)xin + pix*CIN + kc*32 + quad*8;
                float xv[8];
                if (v) {
                    *(float4*)(xv+0) = *(const float4*)(af);
                    *(float4*)(xv+4) = *(const float4*)(af + 4);
                } else {
#pragma unroll
                    for (int jj = 0; jj < 8; ++jj) xv[jj] = 0.0f;
                }
#pragma unroll
                for (int jj = 0; jj < 8; ++jj) {
                    __bf16 th, tm, tl;
                    split3f(xv[jj], th, tm, tl);
                    ah[jj] = th; am_[jj] = tm; al_[jj] = tl;
                }
            } else {
                const __hip_bfloat16* ap = (const __hip_bfloat16*)xin
                    + pix*(3*CIN) + kc*32 + quad*8;
                ah  = v ? ld_bf16x8(ap)           : zv;
                am_ = v ? ld_bf16x8(ap + CIN)     : zv;
                al_ = v ? ld_bf16x8(ap + 2*CIN)   : zv;
            }
#pragma unroll
            for (int nf = 0; nf < NFB; ++nf) {
                bf16x8_t bh = ldsB[(0*NFB + nf)*KC*64 + kc*64 + lane];
                bf16x8_t bm = ldsB[(1*NFB + nf)*KC*64 + kc*64 + lane];
                bf16x8_t bl = ldsB[(2*NFB + nf)*KC*64 + kc*64 + lane];
                acc[nf] = __builtin_amdgcn_mfma_f32_16x16x32_bf16(al_, bh, acc[nf], 0, 0, 0);
                acc[nf] = __builtin_amdgcn_mfma_f32_16x16x32_bf16(ah,  bl, acc[nf], 0, 0, 0);
                acc[nf] = __builtin_amdgcn_mfma_f32_16x16x32_bf16(am_, bm, acc[nf], 0, 0, 0);
                acc[nf] = __builtin_amdgcn_mfma_f32_16x16x32_bf16(am_, bh, acc[nf], 0, 0, 0);
                acc[nf] = __builtin_amdgcn_mfma_f32_16x16x32_bf16(ah,  bm, acc[nf], 0, 0, 0);
                acc[nf] = __builtin_amdgcn_mfma_f32_16x16x32_bf16(ah,  bh, acc[nf], 0, 0, 0);
            }
        }
    }

#pragma unroll
    for (int nf = 0; nf < NFB; ++nf) {
#pragma unroll
        for (int i = 0; i < 4; ++i) {
            int mo = blockIdx.x*64 + wave*16 + quad*4 + i;
            int wo = mo & (OW-1), ho = (mo >> OWL) & (OW-1), no = mo >> (2*OWL);
            size_t opix = (size_t)(no*OW + ho)*OW + wo;
            float vv = acc[nf][i];
            if (ACT) vv = fmaxf(vv, 0.0f);
            if (OUTF32) {
                yf[opix*COUT + (nf0 + nf)*16 + l15] = vv;
            } else {
                __bf16 h, mm2, l;
                split3f(vv, h, mm2, l);
                __bf16* yb = (__bf16*)yout + opix*(3*COUT) + (nf0 + nf)*16 + l15;
                yb[0]        = h;
                yb[COUT]     = mm2;
                yb[2*COUT]   = l;
            }
        }
    }
}

// ---------------------------------------------------------------------------
// MFMA decoder layer, B staged per-tap in LDS (validated).
// ---------------------------------------------------------------------------
template<int CIN,int COUT,int SWL,int CONVT,int NSPLIT>
__global__ __launch_bounds__(256) void mfma_decB(
    const __hip_bfloat16* __restrict__ xin,
    const __hip_bfloat16* __restrict__ wdk,
    const float* __restrict__ bias,
    __hip_bfloat16* __restrict__ yout)
{
    constexpr int SW = 1 << SWL;
    constexpr int NF = COUT / 16, KC = CIN / 32;
    constexpr int NFB = NF / NSPLIT;
    constexpr int CHUNK8 = NFB*KC*64;
    __shared__ bf16x8_t ldsB[CHUNK8];

    const int ph = CONVT ? (int)(blockIdx.y >> 1) : 0;
    const int pw = CONVT ? (int)(blockIdx.y & 1) : 0;
    const int nf0 = (CONVT ? (int)blockIdx.z : (int)blockIdx.y) * NFB;
    const int t = threadIdx.x;
    const int wave = t >> 6, lane = t & 63;
    const int l15 = lane & 15, quad = lane >> 4;

    const int m  = blockIdx.x*64 + wave*16 + l15;
    const int wp_ = m & (SW-1);
    const int hp_ = (m >> SWL) & (SW-1);
    const int np_ = m >> (2*SWL);

    f32x4_t acc[NFB];
#pragma unroll
    for (int nf = 0; nf < NFB; ++nf) {
        float bv = bias[(nf0 + nf)*16 + l15];
        acc[nf][0] = bv; acc[nf][1] = bv; acc[nf][2] = bv; acc[nf][3] = bv;
    }
    const bf16x8_t zv = zero_bf16x8();

    for (int tap = 0; tap < 4; ++tap) {
        const int rr = tap >> 1, ss = tap & 1;
        const int widx = CONVT ? ((ph + 2*rr)*4 + (pw + 2*ss)) : tap;
        __syncthreads();
        {
            const bf16x8_t* base = (const bf16x8_t*)wdk
                + (size_t)widx*(NF*KC*64) + (size_t)nf0*KC*64;
            for (int i8 = t; i8 < CHUNK8; i8 += 256) ldsB[i8] = base[i8];
        }
        __syncthreads();

        const int hi = hp_ + ph - 1 + rr;
        const int wi = wp_ + pw - 1 + ss;
        const bool v = (hi >= 0) && (hi < SW) && (wi >= 0) && (wi < SW);
        const int hic = v ? hi : 0, wic = v ? wi : 0;
        const __hip_bfloat16* ap = xin + (size_t)((np_*SW + hic)*SW + wic)*CIN + quad*8;
#pragma unroll
        for (int kc = 0; kc < KC; ++kc) {
            bf16x8_t a = v ? ld_bf16x8(ap + kc*32) : zv;
#pragma unroll
            for (int nf = 0; nf < NFB; ++nf) {
                bf16x8_t b = ldsB[(nf*KC + kc)*64 + lane];
                acc[nf] = __builtin_amdgcn_mfma_f32_16x16x32_bf16(a, b, acc[nf], 0, 0, 0);
            }
        }
    }

    constexpr int HOUT = CONVT ? 2*SW : SW;
#pragma unroll
    for (int nf = 0; nf < NFB; ++nf) {
#pragma unroll
        for (int i = 0; i < 4; ++i) {
            int mo = blockIdx.x*64 + wave*16 + quad*4 + i;
            int wo = mo & (SW-1), ho = (mo >> SWL) & (SW-1), no = mo >> (2*SWL);
            int hoo = CONVT ? 2*ho + ph : ho;
            int woo = CONVT ? 2*wo + pw : wo;
            float vv = fmaxf(acc[nf][i], 0.0f);
            yout[((size_t)(no*HOUT + hoo)*HOUT + woo)*COUT + (nf0 + nf)*16 + l15] = __float2bfloat16(vv);
        }
    }
}

// ---------------------------------------------------------------------------
// dec4 via MFMA (validated).
// ---------------------------------------------------------------------------
__global__ __launch_bounds__(256) void dec4_mfma(
    const __hip_bfloat16* __restrict__ x, const __hip_bfloat16* __restrict__ wb,
    const float* __restrict__ bias, float* __restrict__ y)
{
    __shared__ __hip_bfloat16 xs[6*66*40];

    const int n  = blockIdx.x >> 4;
    const int R0 = (blockIdx.x & 15) * 4;
    const int t  = threadIdx.x;
    const int wave = t >> 6, lane = t & 63;
    const int l15 = lane & 15, quad = lane >> 4;

    bf16x8_t wreg[16];
#pragma unroll
    for (int g = 0; g < 16; ++g)
        wreg[g] = ld_bf16x8(wb + (size_t)(g*64 + lane)*8);

    const float bv = (l15 < 3) ? bias[l15] : 0.0f;

    for (int slot = t; slot < 6*66*4; slot += 256) {
        int row = slot / 264;
        int rem = slot - row*264;
        int col = rem >> 2, c8 = rem & 3;
        int xi = R0 - 1 + row, xc = col - 1;
        uint4 val = make_uint4(0u,0u,0u,0u);
        if (xi >= 0 && xi < 64 && xc >= 0 && xc < 64)
            val = *(const uint4*)(x + ((size_t)((n*64 + xi)*64) + xc)*32 + c8*8);
        *(uint4*)(xs + (row*66 + col)*40 + c8*8) = val;
    }
    __syncthreads();

    for (int r4 = 0; r4 < 4; ++r4) {
        bf16x8_t af[3][3];
#pragma unroll
        for (int dr = 0; dr < 3; ++dr)
#pragma unroll
            for (int dc = 0; dc < 3; ++dc)
                af[dr][dc] = *(const bf16x8_t*)(xs
                    + ((r4 + dr)*66 + (wave*16 + l15 + dc))*40 + quad*8);

#pragma unroll
        for (int ph = 0; ph < 2; ++ph)
#pragma unroll
        for (int pw = 0; pw < 2; ++pw) {
            f32x4_t acc;
            acc[0] = bv; acc[1] = bv; acc[2] = bv; acc[3] = bv;
#pragma unroll
            for (int rr = 0; rr < 2; ++rr)
#pragma unroll
            for (int ss = 0; ss < 2; ++ss) {
                const int g = (ph + 2*rr)*4 + (pw + 2*ss);
                acc = __builtin_amdgcn_mfma_f32_16x16x32_bf16(
                          af[ph+rr][pw+ss], wreg[g], acc, 0, 0, 0);
            }
            if (l15 < 3) {
#pragma unroll
                for (int i = 0; i < 4; ++i) {
                    int pc = wave*16 + quad*4 + i;
                    int ho = 2*(R0 + r4) + ph, wo = 2*pc + pw;
                    float vv = 1.0f / (1.0f + __expf(-acc[i]));
                    y[((size_t)(n*128 + ho)*128 + wo)*3 + l15] = vv;
                }
            }
        }
    }
}

__global__ void zero_loss(float* p) {
    if (threadIdx.x == 0 && blockIdx.x == 0) *p = 0.0f;
}

// ---------------------------------------------------------------------------
// VQ via bf16x3 MFMA (validated r11).
// ---------------------------------------------------------------------------
__global__ __launch_bounds__(256) void vq_mfma(
    const float* __restrict__ z, const __hip_bfloat16* __restrict__ wek,
    const float* __restrict__ se, const float* __restrict__ emb,
    __hip_bfloat16* __restrict__ qb, float* __restrict__ idx_out,
    float* __restrict__ loss_out, float loss_scale)
{
    __shared__ float ses[512];
    __shared__ float rv[64*16];
    __shared__ int   ri[64*16];
    __shared__ int   mi[64];
    __shared__ float lred[256];

    const int t = threadIdx.x;
    const int wave = t >> 6, lane = t & 63;
    const int l15 = lane & 15, quad = lane >> 4;
    const int pos0 = blockIdx.x * 64;

    for (int i = t; i < 512; i += 256) ses[i] = se[i];

    const int prow = pos0 + wave*16 + l15;
    bf16x8_t ah[2], am[2], al[2];
#pragma unroll
    for (int kc = 0; kc < 2; ++kc) {
        float xv[8];
        *(float4*)(xv+0) = *(const float4*)(z + (size_t)prow*64 + kc*32 + quad*8);
        *(float4*)(xv+4) = *(const float4*)(z + (size_t)prow*64 + kc*32 + quad*8 + 4);
#pragma unroll
        for (int jj = 0; jj < 8; ++jj) {
            __bf16 th, tm, tl;
            split3f(xv[jj], th, tm, tl);
            ah[kc][jj] = th; am[kc][jj] = tm; al[kc][jj] = tl;
        }
    }

    f32x4_t acc[32];
#pragma unroll
    for (int nf = 0; nf < 32; ++nf) {
        acc[nf][0] = 0.f; acc[nf][1] = 0.f; acc[nf][2] = 0.f; acc[nf][3] = 0.f;
    }

#pragma unroll 8
    for (int nf = 0; nf < 32; ++nf) {
#pragma unroll
        for (int kc = 0; kc < 2; ++kc) {
            const bf16x8_t* bp = (const bf16x8_t*)wek + (size_t)((nf*2 + kc)*3)*64 + lane;
            bf16x8_t bh = bp[0];
            bf16x8_t bm = bp[64];
            bf16x8_t bl = bp[128];
            acc[nf] = __builtin_amdgcn_mfma_f32_16x16x32_bf16(al[kc], bh, acc[nf], 0, 0, 0);
            acc[nf] = __builtin_amdgcn_mfma_f32_16x16x32_bf16(ah[kc], bl, acc[nf], 0, 0, 0);
            acc[nf] = __builtin_amdgcn_mfma_f32_16x16x32_bf16(am[kc], bm, acc[nf], 0, 0, 0);
            acc[nf] = __builtin_amdgcn_mfma_f32_16x16x32_bf16(am[kc], bh, acc[nf], 0, 0, 0);
            acc[nf] = __builtin_amdgcn_mfma_f32_16x16x32_bf16(ah[kc], bm, acc[nf], 0, 0, 0);
            acc[nf] = __builtin_amdgcn_mfma_f32_16x16x32_bf16(ah[kc], bh, acc[nf], 0, 0, 0);
        }
    }
    __syncthreads();

    float best[4]; int bidx[4];
#pragma unroll
    for (int i = 0; i < 4; ++i) { best[i] = 3.4e38f; bidx[i] = 0; }
#pragma unroll
    for (int nf = 0; nf < 32; ++nf) {
        const int code = nf*16 + l15;
        const float seC = ses[code];
#pragma unroll
        for (int i = 0; i < 4; ++i) {
            float d = fmaf(-2.0f, acc[nf][i], seC);
            if (d < best[i]) { best[i] = d; bidx[i] = code; }
        }
    }
#pragma unroll
    for (int i = 0; i < 4; ++i) {
        int p = wave*16 + quad*4 + i;
        rv[p*16 + l15] = best[i];
        ri[p*16 + l15] = bidx[i];
    }
    __syncthreads();
    if (t < 64) {
        float bd = rv[t*16]; int bi = ri[t*16];
#pragma unroll
        for (int k = 1; k < 16; ++k) {
            float v = rv[t*16 + k]; int id = ri[t*16 + k];
            if (v < bd || (v == bd && id < bi)) { bd = v; bi = id; }
        }
        mi[t] = bi;
        idx_out[pos0 + t] = (float)bi;
    }
    __syncthreads();

    float part = 0.0f;
    for (int j = t; j < 4096; j += 256) {
        int p = j >> 6, d = j & 63;
        float ev = emb[(size_t)mi[p]*64 + d];
        float zz = z[(size_t)(pos0 + p)*64 + d];
        float df = ev - zz;
        part = fmaf(df, df, part);
        qb[(size_t)pos0*64 + j] = __float2bfloat16(ev);
    }
    lred[t] = part;
    __syncthreads();
    for (int s = 128; s > 0; s >>= 1) {
        if (t < s) lred[t] += lred[t + s];
        __syncthreads();
    }
    if (t == 0) atomicAdd(loss_out, lred[0] * loss_scale);
}

extern "C" void kernel_launch(void* const* d_in, const int* in_sizes, int n_in,
                              void* d_out, int out_size, void* d_ws, size_t ws_size,
                              hipStream_t stream)
{
    const float* x   = (const float*)d_in[0];
    const float* ew1 = (const float*)d_in[1];  const float* eb1 = (const float*)d_in[2];
    const float* ew2 = (const float*)d_in[3];  const float* eb2 = (const float*)d_in[4];
    const float* ew3 = (const float*)d_in[5];  const float* eb3 = (const float*)d_in[6];
    const float* ew4 = (const float*)d_in[7];  const float* eb4 = (const float*)d_in[8];
    const float* emb = (const float*)d_in[9];
    const float* dw1 = (const float*)d_in[10]; const float* db1 = (const float*)d_in[11];
    const float* dw2 = (const float*)d_in[12]; const float* db2 = (const float*)d_in[13];
    const float* dw3 = (const float*)d_in[14]; const float* db3 = (const float*)d_in[15];
    const float* dw4 = (const float*)d_in[16]; const float* db4 = (const float*)d_in[17];

    float* outy = (float*)d_out;          // y: 6291456
    float* outl = outy + 6291456;         // loss: 1
    float* outi = outl + 1;               // idx: 32768

    // Workspace layout (time-multiplexed; peak < 134,217,728 B):
    char* W = (char*)d_ws;
    float*          e1  = (float*)         (W + 0);          // 64 MB [0,67108864)
    __hip_bfloat16* e2p = (__hip_bfloat16*)(W + 67108864);   // 50.3 MB
    __hip_bfloat16* e3p = (__hip_bfloat16*)(W + 0);          // 25.2 MB (over dead e1)
    float*          z   = (float*)         (W + 25165824);   // 8 MB
    __hip_bfloat16* qb  = (__hip_bfloat16*)(W + 33554432);   // 4 MB
    __hip_bfloat16* d1o = (__hip_bfloat16*)(W + 37748736);   // 8.4 MB
    __hip_bfloat16* d2o = (__hip_bfloat16*)(W + 46137344);   // 16.8 MB
    __hip_bfloat16* d3o = (__hip_bfloat16*)(W + 67108864);   // 33.6 MB (over dead e2p)
    // persistent weights:
    __hip_bfloat16* wp2 = (__hip_bfloat16*)(W + 117440512);  //  98304 el
    __hip_bfloat16* wp3 = wp2 + 98304;                       // 393216 el
    __hip_bfloat16* wp4 = wp3 + 393216;                      //  98304 el
    __hip_bfloat16* wd1 = wp4 + 98304;                       //  32768 el
    __hip_bfloat16* wd2 = wd1 + 32768;                       // 131072 el
    __hip_bfloat16* wd3 = wd2 + 131072;                      //  32768 el
    __hip_bfloat16* wb4 = wd3 + 32768;                       //   8192 el
    __hip_bfloat16* wek = wb4 + 8192;                        //  98304 el
    float*          seb = (float*)(wek + 98304);             //    512 el
    __hip_bfloat16* wb1 = (__hip_bfloat16*)(seb + 512);      //   6144 el

    // ---- weight prep ----
    hipLaunchKernelGGL(prep_wpk, dim3(384),  dim3(256), 0, stream, ew2, wp2, 16, 32, 64);
    hipLaunchKernelGGL(prep_wpk, dim3(1536), dim3(256), 0, stream, ew3, wp3, 16, 64, 128);
    hipLaunchKernelGGL(prep_wpk, dim3(384),  dim3(256), 0, stream, ew4, wp4, 4, 128, 64);
    hipLaunchKernelGGL(prep_wdk, dim3(128),  dim3(256), 0, stream, dw1, wd1, 4, 64, 128);
    hipLaunchKernelGGL(prep_wdk, dim3(512),  dim3(256), 0, stream, dw2, wd2, 16, 128, 64);
    hipLaunchKernelGGL(prep_wdk, dim3(128),  dim3(256), 0, stream, dw3, wd3, 16, 64, 32);
    hipLaunchKernelGGL(prep_wb4, dim3(32),   dim3(256), 0, stream, dw4, wb4);
    hipLaunchKernelGGL(prep_wek, dim3(384),  dim3(256), 0, stream, emb, wek);
    hipLaunchKernelGGL(prep_se,  dim3(2),    dim3(256), 0, stream, emb, seb);
    hipLaunchKernelGGL(prep_wb1, dim3(24),   dim3(256), 0, stream, ew1, wb1);

    // ---- encoder (fp32-accurate bf16x3 MFMA) ----
    hipLaunchKernelGGL(enc1_mfma, dim3(8192), dim3(256), 0, stream, x, wb1, eb1, e1);
    hipLaunchKernelGGL((mfma_encB<4,4,32,64,6,5,2,1,1,1,0,1>), dim3(2048), dim3(256), 0, stream,
                       (const void*)e1, wp2, eb2, e2p, (float*)nullptr);
    hipLaunchKernelGGL((mfma_encB<4,4,64,128,5,4,2,1,1,0,0,4>), dim3(512,4), dim3(256), 0, stream,
                       (const void*)e2p, wp3, eb3, e3p, (float*)nullptr);
    hipLaunchKernelGGL((mfma_encB<2,2,128,64,4,4,1,0,0,0,1,2>), dim3(512,2), dim3(256), 0, stream,
                       (const void*)e3p, wp4, eb4, (__hip_bfloat16*)nullptr, z);

    // ---- vector quantizer (MFMA) ----
    hipLaunchKernelGGL(zero_loss, dim3(1), dim3(64), 0, stream, outl);
    hipLaunchKernelGGL(vq_mfma, dim3(512), dim3(256), 0, stream,
                       z, wek, seb, emb, qb, outi, outl, 0.25f / 2097152.0f);

    // ---- decoder (bf16 MFMA, B in LDS) ----
    hipLaunchKernelGGL((mfma_decB<64,128,4,0,2>), dim3(512,2),  dim3(256), 0, stream, qb,  wd1, db1, d1o);
    hipLaunchKernelGGL((mfma_decB<128,64,4,1,1>), dim3(512,4),  dim3(256), 0, stream, d1o, wd2, db2, d2o);
    hipLaunchKernelGGL((mfma_decB<64,32,5,1,1>),  dim3(2048,4), dim3(256), 0, stream, d2o, wd3, db3, d3o);
    hipLaunchKernelGGL(dec4_mfma, dim3(2048), dim3(256), 0, stream, d3o, wb4, db4, outy);
}

// Round 13
// 482.822 us; speedup vs baseline: 1.1357x; 1.1357x over previous
//
#include <hip/hip_runtime.h>
#include <hip/hip_bf16.h>

typedef __bf16 bf16x8_t __attribute__((ext_vector_type(8)));
typedef float  f32x4_t  __attribute__((ext_vector_type(4)));

__device__ inline bf16x8_t ld_bf16x8(const __hip_bfloat16* p) {
    return *reinterpret_cast<const bf16x8_t*>(p);
}
__device__ inline bf16x8_t zero_bf16x8() {
    bf16x8_t z;
#pragma unroll
    for (int i = 0; i < 8; ++i) z[i] = (__bf16)0.0f;
    return z;
}

// Async global->LDS 16B copy (gfx950). LDS side must be lane-contiguous:
// our staging loops use lds addr = (t + 256k)*16 which satisfies
// wave-uniform base + lane*16.
__device__ inline void g2lds16(const bf16x8_t* g, bf16x8_t* l) {
    __builtin_amdgcn_global_load_lds(
        (const __attribute__((address_space(1))) unsigned int*)g,
        (__attribute__((address_space(3))) unsigned int*)l,
        16, 0, 0);
}

// Exact 3-way bf16 split: v == h + m + l exactly (truncation-based).
__device__ inline void split3f(float v, __bf16& h, __bf16& m, __bf16& l) {
    unsigned u;  __builtin_memcpy(&u, &v, 4);
    unsigned uh = u & 0xffff0000u;
    float fh;    __builtin_memcpy(&fh, &uh, 4);
    float r = v - fh;
    unsigned ur; __builtin_memcpy(&ur, &r, 4);
    unsigned um = ur & 0xffff0000u;
    float fm;    __builtin_memcpy(&fm, &um, 4);
    float r2 = r - fm;
    unsigned ul; __builtin_memcpy(&ul, &r2, 4);
    unsigned short hs = (unsigned short)(uh >> 16);
    unsigned short ms = (unsigned short)(um >> 16);
    unsigned short ls = (unsigned short)(ul >> 16);
    __builtin_memcpy(&h, &hs, 2);
    __builtin_memcpy(&m, &ms, 2);
    __builtin_memcpy(&l, &ls, 2);
}

// ---------------------------------------------------------------------------
// enc1 via MFMA (r12): conv 4x4 s2 pad1, CIN=3, COUT=32, bf16x3 exact-split.
// ---------------------------------------------------------------------------
__global__ __launch_bounds__(256) void enc1_mfma(
    const float* __restrict__ x,
    const __hip_bfloat16* __restrict__ wb,
    const float* __restrict__ bias, float* __restrict__ y)
{
    __shared__ bf16x8_t xs8[1584];
    __hip_bfloat16* xs = (__hip_bfloat16*)xs8;

    const int n  = blockIdx.x >> 6;
    const int ho = blockIdx.x & 63;
    const int t  = threadIdx.x;
    const int wave = t >> 6, lane = t & 63;
    const int l15 = lane & 15, quad = lane >> 4;

    bf16x8_t bf[2][2][3];
#pragma unroll
    for (int rp = 0; rp < 2; ++rp)
#pragma unroll
        for (int tile = 0; tile < 2; ++tile)
#pragma unroll
            for (int pl = 0; pl < 3; ++pl)
                bf[rp][tile][pl] = ld_bf16x8(wb + (size_t)((((rp*2 + tile)*3 + pl)*64 + lane))*8);

    const int hi0 = 2*ho - 1;
    for (int slot = t; slot < 4*132*4; slot += 256) {
        int row = slot / 528;
        int rem = slot - row*528;
        int col = rem >> 2, c = rem & 3;
        int hi = hi0 + row, wi = col - 1;
        float v = 0.0f;
        if (c < 3 && hi >= 0 && hi < 128 && wi >= 0 && wi < 128)
            v = x[((size_t)((n*128 + hi))*128 + wi)*3 + c];
        __bf16 h, m, l;
        split3f(v, h, m, l);
        xs[0*2112 + slot] = *(__hip_bfloat16*)&h;
        xs[1*2112 + slot] = *(__hip_bfloat16*)&m;
        xs[2*2112 + slot] = *(__hip_bfloat16*)&l;
    }
    __syncthreads();

    const int wo = wave*16 + l15;
    f32x4_t acc[2];
#pragma unroll
    for (int tile = 0; tile < 2; ++tile) {
        float bv = bias[tile*16 + l15];
        acc[tile][0] = bv; acc[tile][1] = bv; acc[tile][2] = bv; acc[tile][3] = bv;
    }

#pragma unroll
    for (int rp = 0; rp < 2; ++rp) {
        const int off = (2*rp + (quad >> 1))*528 + 8*wo + (quad & 1)*8;
        bf16x8_t ah = *(const bf16x8_t*)(xs + 0*2112 + off);
        bf16x8_t am = *(const bf16x8_t*)(xs + 1*2112 + off);
        bf16x8_t al = *(const bf16x8_t*)(xs + 2*2112 + off);
#pragma unroll
        for (int tile = 0; tile < 2; ++tile) {
            acc[tile] = __builtin_amdgcn_mfma_f32_16x16x32_bf16(al, bf[rp][tile][0], acc[tile], 0, 0, 0);
            acc[tile] = __builtin_amdgcn_mfma_f32_16x16x32_bf16(ah, bf[rp][tile][2], acc[tile], 0, 0, 0);
            acc[tile] = __builtin_amdgcn_mfma_f32_16x16x32_bf16(am, bf[rp][tile][1], acc[tile], 0, 0, 0);
            acc[tile] = __builtin_amdgcn_mfma_f32_16x16x32_bf16(am, bf[rp][tile][0], acc[tile], 0, 0, 0);
            acc[tile] = __builtin_amdgcn_mfma_f32_16x16x32_bf16(ah, bf[rp][tile][1], acc[tile], 0, 0, 0);
            acc[tile] = __builtin_amdgcn_mfma_f32_16x16x32_bf16(ah, bf[rp][tile][0], acc[tile], 0, 0, 0);
        }
    }

#pragma unroll
    for (int tile = 0; tile < 2; ++tile)
#pragma unroll
        for (int i = 0; i < 4; ++i) {
            int wo2 = wave*16 + quad*4 + i;
            float vv = fmaxf(acc[tile][i], 0.0f);
            y[((size_t)((n*64 + ho))*64 + wo2)*32 + tile*16 + l15] = vv;
        }
}

__global__ void prep_wb1(const float* __restrict__ w, __hip_bfloat16* __restrict__ out)
{
    int i = blockIdx.x*256 + threadIdx.x;
    if (i >= 2*2*3*64*8) return;
    int j = i & 7;
    int lane = (i >> 3) & 63;
    int g = i >> 9;
    int pl = g % 3; g /= 3;
    int tile = g & 1, rp = g >> 1;
    int k = (lane >> 4)*8 + j;
    int c = k & 3, s = (k >> 2) & 3, lr = k >> 4;
    int f = tile*16 + (lane & 15);
    float v = 0.0f;
    if (c < 3) v = w[(((rp*2 + lr)*4 + s)*3 + c)*32 + f];
    __bf16 h, m, l;
    split3f(v, h, m, l);
    ((__bf16*)out)[i] = (pl == 0) ? h : (pl == 1) ? m : l;
}

// ---------------------------------------------------------------------------
// Weight prep (validated layouts).
// ---------------------------------------------------------------------------
__global__ void prep_wpk(const float* __restrict__ w, __hip_bfloat16* __restrict__ out,
                         int TAPS, int CIN, int COUT)
{
    const int NF = COUT >> 4, KC = CIN >> 5;
    int total = TAPS*3*NF*KC*512;
    int i = blockIdx.x*256 + threadIdx.x;
    if (i >= total) return;
    int tmp = i;
    int j = tmp & 7;      tmp >>= 3;
    int lane = tmp & 63;  tmp >>= 6;
    int kc = tmp % KC;    tmp /= KC;
    int nf = tmp % NF;    tmp /= NF;
    int plane = tmp % 3;  int tap = tmp / 3;
    int l15 = lane & 15, quad = lane >> 4;
    int f = nf*16 + l15;
    int c = kc*32 + quad*8 + j;
    float v = w[(tap*CIN + c)*COUT + f];
    __bf16 h, m, l;
    split3f(v, h, m, l);
    ((__bf16*)out)[i] = (plane == 0) ? h : (plane == 1) ? m : l;
}

__global__ void prep_wdk(const float* __restrict__ w, __hip_bfloat16* __restrict__ out,
                         int TAPS, int CIN, int COUT)
{
    const int NF = COUT >> 4, KC = CIN >> 5;
    int total = TAPS*NF*KC*512;
    int i = blockIdx.x*256 + threadIdx.x;
    if (i >= total) return;
    int tmp = i;
    int j = tmp & 7;      tmp >>= 3;
    int lane = tmp & 63;  tmp >>= 6;
    int kc = tmp % KC;    tmp /= KC;
    int nf = tmp % NF;    tmp /= NF;
    int tap = tmp;
    int l15 = lane & 15, quad = lane >> 4;
    int f = nf*16 + l15;
    int c = kc*32 + quad*8 + j;
    out[i] = __float2bfloat16(w[(tap*CIN + c)*COUT + f]);
}

__global__ void prep_wb4(const float* __restrict__ w, __hip_bfloat16* __restrict__ out)
{
    int i = blockIdx.x*256 + threadIdx.x;
    if (i >= 16*64*8) return;
    int j = i & 7;
    int lane = (i >> 3) & 63;
    int g = i >> 9;
    int f = lane & 15;
    int c = (lane >> 4)*8 + j;
    float v = (f < 3) ? w[g*96 + c*3 + f] : 0.0f;
    out[i] = __float2bfloat16(v);
}

__global__ void prep_wek(const float* __restrict__ emb, __hip_bfloat16* __restrict__ out)
{
    int i = blockIdx.x*256 + threadIdx.x;
    if (i >= 32*2*3*512) return;
    int tmp = i;
    int j = tmp & 7;      tmp >>= 3;
    int lane = tmp & 63;  tmp >>= 6;
    int plane = tmp % 3;  tmp /= 3;
    int kc = tmp & 1;     int nf = tmp >> 1;
    int code = nf*16 + (lane & 15);
    int c = kc*32 + (lane >> 4)*8 + j;
    float v = emb[code*64 + c];
    __bf16 h, m, l;
    split3f(v, h, m, l);
    ((__bf16*)out)[i] = (plane == 0) ? h : (plane == 1) ? m : l;
}

__global__ void prep_se(const float* __restrict__ emb, float* __restrict__ se)
{
    int k = blockIdx.x*256 + threadIdx.x;
    if (k >= 512) return;
    float s = 0.0f;
    for (int d = 0; d < 64; ++d) {
        float e = emb[k*64 + d];
        s = fmaf(e, e, s);
    }
    se[k] = s;
}

// ---------------------------------------------------------------------------
// bf16x3 MFMA encoder conv, B staged per-tap in LDS via global_load_lds.
// ---------------------------------------------------------------------------
template<int R,int S,int CIN,int COUT,int IWL,int OWL,int STR,int PAD,int ACT,int INF32,int OUTF32,int NSPLIT>
__global__ __launch_bounds__(256) void mfma_encB(
    const void* __restrict__ xin,
    const __hip_bfloat16* __restrict__ wpk,
    const float* __restrict__ bias,
    __hip_bfloat16* __restrict__ yout,
    float* __restrict__ yf)
{
    constexpr int IW = 1 << IWL, OW = 1 << OWL;
    constexpr int NF = COUT / 16, KC = CIN / 32, TAPS = R*S;
    constexpr int NFB = NF / NSPLIT;
    constexpr int PIECE = NFB*KC*64;
    constexpr int CHUNK8 = 3*PIECE;
    __shared__ bf16x8_t ldsB[CHUNK8];

    const int nf0 = (int)blockIdx.y * NFB;
    const int t = threadIdx.x;
    const int wave = t >> 6, lane = t & 63;
    const int l15 = lane & 15, quad = lane >> 4;

    const int m  = blockIdx.x*64 + wave*16 + l15;
    const int wp_ = m & (OW-1);
    const int hp_ = (m >> OWL) & (OW-1);
    const int np_ = m >> (2*OWL);

    f32x4_t acc[NFB];
#pragma unroll
    for (int nf = 0; nf < NFB; ++nf) {
        float bv = bias[(nf0 + nf)*16 + l15];
        acc[nf][0] = bv; acc[nf][1] = bv; acc[nf][2] = bv; acc[nf][3] = bv;
    }
    const bf16x8_t zv = zero_bf16x8();

    for (int tap = 0; tap < TAPS; ++tap) {
        __syncthreads();
        {
            const bf16x8_t* base = (const bf16x8_t*)wpk + (size_t)tap*(3*NF*KC*64);
#pragma unroll
            for (int i8 = t; i8 < CHUNK8; i8 += 256) {
                int plane = i8 / PIECE;
                int rem = i8 - plane*PIECE;
                g2lds16(base + (size_t)(plane*NF + nf0)*KC*64 + rem, ldsB + i8);
            }
        }
        __syncthreads();

        const int r = tap / S, s = tap % S;
        const int hi = hp_*STR - PAD + r;
        const int wi = wp_*STR - PAD + s;
        const bool v = (hi >= 0) && (hi < IW) && (wi >= 0) && (wi < IW);
        const int hic = v ? hi : 0, wic = v ? wi : 0;
        const size_t pix = (size_t)(np_*IW + hic)*IW + wic;

#pragma unroll
        for (int kc = 0; kc < KC; ++kc) {
            bf16x8_t ah, am_, al_;
            if (INF32) {
                const float* af = (const float*)xin + pix*CIN + kc*32 + quad*8;
                float xv[8];
                if (v) {
                    *(float4*)(xv+0) = *(const float4*)(af);
                    *(float4*)(xv+4) = *(const float4*)(af + 4);
                } else {
#pragma unroll
                    for (int jj = 0; jj < 8; ++jj) xv[jj] = 0.0f;
                }
#pragma unroll
                for (int jj = 0; jj < 8; ++jj) {
                    __bf16 th, tm, tl;
                    split3f(xv[jj], th, tm, tl);
                    ah[jj] = th; am_[jj] = tm; al_[jj] = tl;
                }
            } else {
                const __hip_bfloat16* ap = (const __hip_bfloat16*)xin
                    + pix*(3*CIN) + kc*32 + quad*8;
                ah  = v ? ld_bf16x8(ap)           : zv;
                am_ = v ? ld_bf16x8(ap + CIN)     : zv;
                al_ = v ? ld_bf16x8(ap + 2*CIN)   : zv;
            }
#pragma unroll
            for (int nf = 0; nf < NFB; ++nf) {
                bf16x8_t bh = ldsB[(0*NFB + nf)*KC*64 + kc*64 + lane];
                bf16x8_t bm = ldsB[(1*NFB + nf)*KC*64 + kc*64 + lane];
                bf16x8_t bl = ldsB[(2*NFB + nf)*KC*64 + kc*64 + lane];
                acc[nf] = __builtin_amdgcn_mfma_f32_16x16x32_bf16(al_, bh, acc[nf], 0, 0, 0);
                acc[nf] = __builtin_amdgcn_mfma_f32_16x16x32_bf16(ah,  bl, acc[nf], 0, 0, 0);
                acc[nf] = __builtin_amdgcn_mfma_f32_16x16x32_bf16(am_, bm, acc[nf], 0, 0, 0);
                acc[nf] = __builtin_amdgcn_mfma_f32_16x16x32_bf16(am_, bh, acc[nf], 0, 0, 0);
                acc[nf] = __builtin_amdgcn_mfma_f32_16x16x32_bf16(ah,  bm, acc[nf], 0, 0, 0);
                acc[nf] = __builtin_amdgcn_mfma_f32_16x16x32_bf16(ah,  bh, acc[nf], 0, 0, 0);
            }
        }
    }

#pragma unroll
    for (int nf = 0; nf < NFB; ++nf) {
#pragma unroll
        for (int i = 0; i < 4; ++i) {
            int mo = blockIdx.x*64 + wave*16 + quad*4 + i;
            int wo = mo & (OW-1), ho = (mo >> OWL) & (OW-1), no = mo >> (2*OWL);
            size_t opix = (size_t)(no*OW + ho)*OW + wo;
            float vv = acc[nf][i];
            if (ACT) vv = fmaxf(vv, 0.0f);
            if (OUTF32) {
                yf[opix*COUT + (nf0 + nf)*16 + l15] = vv;
            } else {
                __bf16 h, mm2, l;
                split3f(vv, h, mm2, l);
                __bf16* yb = (__bf16*)yout + opix*(3*COUT) + (nf0 + nf)*16 + l15;
                yb[0]        = h;
                yb[COUT]     = mm2;
                yb[2*COUT]   = l;
            }
        }
    }
}

// ---------------------------------------------------------------------------
// MFMA decoder layer, B staged per-tap in LDS via global_load_lds.
// ---------------------------------------------------------------------------
template<int CIN,int COUT,int SWL,int CONVT,int NSPLIT>
__global__ __launch_bounds__(256) void mfma_decB(
    const __hip_bfloat16* __restrict__ xin,
    const __hip_bfloat16* __restrict__ wdk,
    const float* __restrict__ bias,
    __hip_bfloat16* __restrict__ yout)
{
    constexpr int SW = 1 << SWL;
    constexpr int NF = COUT / 16, KC = CIN / 32;
    constexpr int NFB = NF / NSPLIT;
    constexpr int CHUNK8 = NFB*KC*64;
    __shared__ bf16x8_t ldsB[CHUNK8];

    const int ph = CONVT ? (int)(blockIdx.y >> 1) : 0;
    const int pw = CONVT ? (int)(blockIdx.y & 1) : 0;
    const int nf0 = (CONVT ? (int)blockIdx.z : (int)blockIdx.y) * NFB;
    const int t = threadIdx.x;
    const int wave = t >> 6, lane = t & 63;
    const int l15 = lane & 15, quad = lane >> 4;

    const int m  = blockIdx.x*64 + wave*16 + l15;
    const int wp_ = m & (SW-1);
    const int hp_ = (m >> SWL) & (SW-1);
    const int np_ = m >> (2*SWL);

    f32x4_t acc[NFB];
#pragma unroll
    for (int nf = 0; nf < NFB; ++nf) {
        float bv = bias[(nf0 + nf)*16 + l15];
        acc[nf][0] = bv; acc[nf][1] = bv; acc[nf][2] = bv; acc[nf][3] = bv;
    }
    const bf16x8_t zv = zero_bf16x8();

    for (int tap = 0; tap < 4; ++tap) {
        const int rr = tap >> 1, ss = tap & 1;
        const int widx = CONVT ? ((ph + 2*rr)*4 + (pw + 2*ss)) : tap;
        __syncthreads();
        {
            const bf16x8_t* base = (const bf16x8_t*)wdk
                + (size_t)widx*(NF*KC*64) + (size_t)nf0*KC*64;
#pragma unroll
            for (int i8 = t; i8 < CHUNK8; i8 += 256)
                g2lds16(base + i8, ldsB + i8);
        }
        __syncthreads();

        const int hi = hp_ + ph - 1 + rr;
        const int wi = wp_ + pw - 1 + ss;
        const bool v = (hi >= 0) && (hi < SW) && (wi >= 0) && (wi < SW);
        const int hic = v ? hi : 0, wic = v ? wi : 0;
        const __hip_bfloat16* ap = xin + (size_t)((np_*SW + hic)*SW + wic)*CIN + quad*8;
#pragma unroll
        for (int kc = 0; kc < KC; ++kc) {
            bf16x8_t a = v ? ld_bf16x8(ap + kc*32) : zv;
#pragma unroll
            for (int nf = 0; nf < NFB; ++nf) {
                bf16x8_t b = ldsB[(nf*KC + kc)*64 + lane];
                acc[nf] = __builtin_amdgcn_mfma_f32_16x16x32_bf16(a, b, acc[nf], 0, 0, 0);
            }
        }
    }

    constexpr int HOUT = CONVT ? 2*SW : SW;
#pragma unroll
    for (int nf = 0; nf < NFB; ++nf) {
#pragma unroll
        for (int i = 0; i < 4; ++i) {
            int mo = blockIdx.x*64 + wave*16 + quad*4 + i;
            int wo = mo & (SW-1), ho = (mo >> SWL) & (SW-1), no = mo >> (2*SWL);
            int hoo = CONVT ? 2*ho + ph : ho;
            int woo = CONVT ? 2*wo + pw : wo;
            float vv = fmaxf(acc[nf][i], 0.0f);
            yout[((size_t)(no*HOUT + hoo)*HOUT + woo)*COUT + (nf0 + nf)*16 + l15] = __float2bfloat16(vv);
        }
    }
}

// ---------------------------------------------------------------------------
// dec4 via MFMA (validated).
// ---------------------------------------------------------------------------
__global__ __launch_bounds__(256) void dec4_mfma(
    const __hip_bfloat16* __restrict__ x, const __hip_bfloat16* __restrict__ wb,
    const float* __restrict__ bias, float* __restrict__ y)
{
    __shared__ __hip_bfloat16 xs[6*66*40];

    const int n  = blockIdx.x >> 4;
    const int R0 = (blockIdx.x & 15) * 4;
    const int t  = threadIdx.x;
    const int wave = t >> 6, lane = t & 63;
    const int l15 = lane & 15, quad = lane >> 4;

    bf16x8_t wreg[16];
#pragma unroll
    for (int g = 0; g < 16; ++g)
        wreg[g] = ld_bf16x8(wb + (size_t)(g*64 + lane)*8);

    const float bv = (l15 < 3) ? bias[l15] : 0.0f;

    for (int slot = t; slot < 6*66*4; slot += 256) {
        int row = slot / 264;
        int rem = slot - row*264;
        int col = rem >> 2, c8 = rem & 3;
        int xi = R0 - 1 + row, xc = col - 1;
        uint4 val = make_uint4(0u,0u,0u,0u);
        if (xi >= 0 && xi < 64 && xc >= 0 && xc < 64)
            val = *(const uint4*)(x + ((size_t)((n*64 + xi)*64) + xc)*32 + c8*8);
        *(uint4*)(xs + (row*66 + col)*40 + c8*8) = val;
    }
    __syncthreads();

    for (int r4 = 0; r4 < 4; ++r4) {
        bf16x8_t af[3][3];
#pragma unroll
        for (int dr = 0; dr < 3; ++dr)
#pragma unroll
            for (int dc = 0; dc < 3; ++dc)
                af[dr][dc] = *(const bf16x8_t*)(xs
                    + ((r4 + dr)*66 + (wave*16 + l15 + dc))*40 + quad*8);

#pragma unroll
        for (int ph = 0; ph < 2; ++ph)
#pragma unroll
        for (int pw = 0; pw < 2; ++pw) {
            f32x4_t acc;
            acc[0] = bv; acc[1] = bv; acc[2] = bv; acc[3] = bv;
#pragma unroll
            for (int rr = 0; rr < 2; ++rr)
#pragma unroll
            for (int ss = 0; ss < 2; ++ss) {
                const int g = (ph + 2*rr)*4 + (pw + 2*ss);
                acc = __builtin_amdgcn_mfma_f32_16x16x32_bf16(
                          af[ph+rr][pw+ss], wreg[g], acc, 0, 0, 0);
            }
            if (l15 < 3) {
#pragma unroll
                for (int i = 0; i < 4; ++i) {
                    int pc = wave*16 + quad*4 + i;
                    int ho = 2*(R0 + r4) + ph, wo = 2*pc + pw;
                    float vv = 1.0f / (1.0f + __expf(-acc[i]));
                    y[((size_t)(n*128 + ho)*128 + wo)*3 + l15] = vv;
                }
            }
        }
    }
}

__global__ void zero_loss(float* p) {
    if (threadIdx.x == 0 && blockIdx.x == 0) *p = 0.0f;
}

// ---------------------------------------------------------------------------
// VQ via bf16x3 MFMA (validated r11).
// ---------------------------------------------------------------------------
__global__ __launch_bounds__(256) void vq_mfma(
    const float* __restrict__ z, const __hip_bfloat16* __restrict__ wek,
    const float* __restrict__ se, const float* __restrict__ emb,
    __hip_bfloat16* __restrict__ qb, float* __restrict__ idx_out,
    float* __restrict__ loss_out, float loss_scale)
{
    __shared__ float ses[512];
    __shared__ float rv[64*16];
    __shared__ int   ri[64*16];
    __shared__ int   mi[64];
    __shared__ float lred[256];

    const int t = threadIdx.x;
    const int wave = t >> 6, lane = t & 63;
    const int l15 = lane & 15, quad = lane >> 4;
    const int pos0 = blockIdx.x * 64;

    for (int i = t; i < 512; i += 256) ses[i] = se[i];

    const int prow = pos0 + wave*16 + l15;
    bf16x8_t ah[2], am[2], al[2];
#pragma unroll
    for (int kc = 0; kc < 2; ++kc) {
        float xv[8];
        *(float4*)(xv+0) = *(const float4*)(z + (size_t)prow*64 + kc*32 + quad*8);
        *(float4*)(xv+4) = *(const float4*)(z + (size_t)prow*64 + kc*32 + quad*8 + 4);
#pragma unroll
        for (int jj = 0; jj < 8; ++jj) {
            __bf16 th, tm, tl;
            split3f(xv[jj], th, tm, tl);
            ah[kc][jj] = th; am[kc][jj] = tm; al[kc][jj] = tl;
        }
    }

    f32x4_t acc[32];
#pragma unroll
    for (int nf = 0; nf < 32; ++nf) {
        acc[nf][0] = 0.f; acc[nf][1] = 0.f; acc[nf][2] = 0.f; acc[nf][3] = 0.f;
    }

#pragma unroll 8
    for (int nf = 0; nf < 32; ++nf) {
#pragma unroll
        for (int kc = 0; kc < 2; ++kc) {
            const bf16x8_t* bp = (const bf16x8_t*)wek + (size_t)((nf*2 + kc)*3)*64 + lane;
            bf16x8_t bh = bp[0];
            bf16x8_t bm = bp[64];
            bf16x8_t bl = bp[128];
            acc[nf] = __builtin_amdgcn_mfma_f32_16x16x32_bf16(al[kc], bh, acc[nf], 0, 0, 0);
            acc[nf] = __builtin_amdgcn_mfma_f32_16x16x32_bf16(ah[kc], bl, acc[nf], 0, 0, 0);
            acc[nf] = __builtin_amdgcn_mfma_f32_16x16x32_bf16(am[kc], bm, acc[nf], 0, 0, 0);
            acc[nf] = __builtin_amdgcn_mfma_f32_16x16x32_bf16(am[kc], bh, acc[nf], 0, 0, 0);
            acc[nf] = __builtin_amdgcn_mfma_f32_16x16x32_bf16(ah[kc], bm, acc[nf], 0, 0, 0);
            acc[nf] = __builtin_amdgcn_mfma_f32_16x16x32_bf16(ah[kc], bh, acc[nf], 0, 0, 0);
        }
    }
    __syncthreads();

    float best[4]; int bidx[4];
#pragma unroll
    for (int i = 0; i < 4; ++i) { best[i] = 3.4e38f; bidx[i] = 0; }
#pragma unroll
    for (int nf = 0; nf < 32; ++nf) {
        const int code = nf*16 + l15;
        const float seC = ses[code];
#pragma unroll
        for (int i = 0; i < 4; ++i) {
            float d = fmaf(-2.0f, acc[nf][i], seC);
            if (d < best[i]) { best[i] = d; bidx[i] = code; }
        }
    }
#pragma unroll
    for (int i = 0; i < 4; ++i) {
        int p = wave*16 + quad*4 + i;
        rv[p*16 + l15] = best[i];
        ri[p*16 + l15] = bidx[i];
    }
    __syncthreads();
    if (t < 64) {
        float bd = rv[t*16]; int bi = ri[t*16];
#pragma unroll
        for (int k = 1; k < 16; ++k) {
            float v = rv[t*16 + k]; int id = ri[t*16 + k];
            if (v < bd || (v == bd && id < bi)) { bd = v; bi = id; }
        }
        mi[t] = bi;
        idx_out[pos0 + t] = (float)bi;
    }
    __syncthreads();

    float part = 0.0f;
    for (int j = t; j < 4096; j += 256) {
        int p = j >> 6, d = j & 63;
        float ev = emb[(size_t)mi[p]*64 + d];
        float zz = z[(size_t)(pos0 + p)*64 + d];
        float df = ev - zz;
        part = fmaf(df, df, part);
        qb[(size_t)pos0*64 + j] = __float2bfloat16(ev);
    }
    lred[t] = part;
    __syncthreads();
    for (int s = 128; s > 0; s >>= 1) {
        if (t < s) lred[t] += lred[t + s];
        __syncthreads();
    }
    if (t == 0) atomicAdd(loss_out, lred[0] * loss_scale);
}

extern "C" void kernel_launch(void* const* d_in, const int* in_sizes, int n_in,
                              void* d_out, int out_size, void* d_ws, size_t ws_size,
                              hipStream_t stream)
{
    const float* x   = (const float*)d_in[0];
    const float* ew1 = (const float*)d_in[1];  const float* eb1 = (const float*)d_in[2];
    const float* ew2 = (const float*)d_in[3];  const float* eb2 = (const float*)d_in[4];
    const float* ew3 = (const float*)d_in[5];  const float* eb3 = (const float*)d_in[6];
    const float* ew4 = (const float*)d_in[7];  const float* eb4 = (const float*)d_in[8];
    const float* emb = (const float*)d_in[9];
    const float* dw1 = (const float*)d_in[10]; const float* db1 = (const float*)d_in[11];
    const float* dw2 = (const float*)d_in[12]; const float* db2 = (const float*)d_in[13];
    const float* dw3 = (const float*)d_in[14]; const float* db3 = (const float*)d_in[15];
    const float* dw4 = (const float*)d_in[16]; const float* db4 = (const float*)d_in[17];

    float* outy = (float*)d_out;          // y: 6291456
    float* outl = outy + 6291456;         // loss: 1
    float* outi = outl + 1;               // idx: 32768

    // Workspace layout (time-multiplexed; peak < 134,217,728 B):
    char* W = (char*)d_ws;
    float*          e1  = (float*)         (W + 0);          // 64 MB [0,67108864)
    __hip_bfloat16* e2p = (__hip_bfloat16*)(W + 67108864);   // 50.3 MB
    __hip_bfloat16* e3p = (__hip_bfloat16*)(W + 0);          // 25.2 MB (over dead e1)
    float*          z   = (float*)         (W + 25165824);   // 8 MB
    __hip_bfloat16* qb  = (__hip_bfloat16*)(W + 33554432);   // 4 MB
    __hip_bfloat16* d1o = (__hip_bfloat16*)(W + 37748736);   // 8.4 MB
    __hip_bfloat16* d2o = (__hip_bfloat16*)(W + 46137344);   // 16.8 MB
    __hip_bfloat16* d3o = (__hip_bfloat16*)(W + 67108864);   // 33.6 MB (over dead e2p)
    // persistent weights:
    __hip_bfloat16* wp2 = (__hip_bfloat16*)(W + 117440512);  //  98304 el
    __hip_bfloat16* wp3 = wp2 + 98304;                       // 393216 el
    __hip_bfloat16* wp4 = wp3 + 393216;                      //  98304 el
    __hip_bfloat16* wd1 = wp4 + 98304;                       //  32768 el
    __hip_bfloat16* wd2 = wd1 + 32768;                       // 131072 el
    __hip_bfloat16* wd3 = wd2 + 131072;                      //  32768 el
    __hip_bfloat16* wb4 = wd3 + 32768;                       //   8192 el
    __hip_bfloat16* wek = wb4 + 8192;                        //  98304 el
    float*          seb = (float*)(wek + 98304);             //    512 el
    __hip_bfloat16* wb1 = (__hip_bfloat16*)(seb + 512);      //   6144 el

    // ---- weight prep ----
    hipLaunchKernelGGL(prep_wpk, dim3(384),  dim3(256), 0, stream, ew2, wp2, 16, 32, 64);
    hipLaunchKernelGGL(prep_wpk, dim3(1536), dim3(256), 0, stream, ew3, wp3, 16, 64, 128);
    hipLaunchKernelGGL(prep_wpk, dim3(384),  dim3(256), 0, stream, ew4, wp4, 4, 128, 64);
    hipLaunchKernelGGL(prep_wdk, dim3(128),  dim3(256), 0, stream, dw1, wd1, 4, 64, 128);
    hipLaunchKernelGGL(prep_wdk, dim3(512),  dim3(256), 0, stream, dw2, wd2, 16, 128, 64);
    hipLaunchKernelGGL(prep_wdk, dim3(128),  dim3(256), 0, stream, dw3, wd3, 16, 64, 32);
    hipLaunchKernelGGL(prep_wb4, dim3(32),   dim3(256), 0, stream, dw4, wb4);
    hipLaunchKernelGGL(prep_wek, dim3(384),  dim3(256), 0, stream, emb, wek);
    hipLaunchKernelGGL(prep_se,  dim3(2),    dim3(256), 0, stream, emb, seb);
    hipLaunchKernelGGL(prep_wb1, dim3(24),   dim3(256), 0, stream, ew1, wb1);

    // ---- encoder (fp32-accurate bf16x3 MFMA) ----
    hipLaunchKernelGGL(enc1_mfma, dim3(8192), dim3(256), 0, stream, x, wb1, eb1, e1);
    hipLaunchKernelGGL((mfma_encB<4,4,32,64,6,5,2,1,1,1,0,1>), dim3(2048), dim3(256), 0, stream,
                       (const void*)e1, wp2, eb2, e2p, (float*)nullptr);
    hipLaunchKernelGGL((mfma_encB<4,4,64,128,5,4,2,1,1,0,0,2>), dim3(512,2), dim3(256), 0, stream,
                       (const void*)e2p, wp3, eb3, e3p, (float*)nullptr);
    hipLaunchKernelGGL((mfma_encB<2,2,128,64,4,4,1,0,0,0,1,2>), dim3(512,2), dim3(256), 0, stream,
                       (const void*)e3p, wp4, eb4, (__hip_bfloat16*)nullptr, z);

    // ---- vector quantizer (MFMA) ----
    hipLaunchKernelGGL(zero_loss, dim3(1), dim3(64), 0, stream, outl);
    hipLaunchKernelGGL(vq_mfma, dim3(512), dim3(256), 0, stream,
                       z, wek, seb, emb, qb, outi, outl, 0.25f / 2097152.0f);

    // ---- decoder (bf16 MFMA, B in LDS) ----
    hipLaunchKernelGGL((mfma_decB<64,128,4,0,2>), dim3(512,2),  dim3(256), 0, stream, qb,  wd1, db1, d1o);
    hipLaunchKernelGGL((mfma_decB<128,64,4,1,1>), dim3(512,4),  dim3(256), 0, stream, d1o, wd2, db2, d2o);
    hipLaunchKernelGGL((mfma_decB<64,32,5,1,1>),  dim3(2048,4), dim3(256), 0, stream, d2o, wd3, db3, d3o);
    hipLaunchKernelGGL(dec4_mfma, dim3(2048), dim3(256), 0, stream, d3o, wb4, db4, outy);
}